// Round 10
// baseline (1530.500 us; speedup 1.0000x reference)
//
#include <hip/hip_runtime.h>
#include <hip/hip_bf16.h>

#define NPIX   65536
#define TT     5
#define CC     10
#define HH     32
#define WIDTH  64
#define KW     32
#define OUTC   10

// ---- workspace layout (float offsets) ----
// LSTM weights grouped by 8 units, k-major, gate-packed: [grp][k][j8][g] rows of 32
#define OFF_L0I    0        // 1280  [grp][c][j8][g]
#define OFF_L0H    1280     // 4096  [grp][k][j8][g]
#define OFF_L1I    5376     // 4096
#define OFF_L1H    9472     // 4096
#define OFF_B0     13568    // 128   [j][g]
#define OFF_B1     13696    // 128
#define OFF_FC1W   13824    // 2048  [k][ch]
#define OFF_FC1B   15872    // 64
#define OFF_CWT2   16384    // 16384 [k][co2][ci] float2  (R8 conv layout)
#define OFF_CB     32768    // 256
#define OFF_FC2W2  33024    // 2048  [m2][ch] float2
#define OFF_FC2B   35072    // 32
#define OFF_FC3W4  35104    // 320   [oc2][m2] float4
#define OFF_FC3B   35424    // 16
#define OFF_GW     35440    // 8
#define OFF_FEATS_A 36864
#define OFF_FEATS_B (36864 + 8388608)

#define STRAIGHT_ATTR_IDX (65025 * 3)

__device__ __forceinline__ float sigf(float x)  { return 1.0f / (1.0f + __expf(-x)); }
__device__ __forceinline__ float tanhf_(float x){ return 1.0f - 2.0f / (__expf(2.0f * x) + 1.0f); }

// ---------------- prep: pack params ----------------
__global__ __launch_bounds__(256, 1)
void prep_kernel(const float* Wih0, const float* Whh0,
                 const float* bih0, const float* bhh0,
                 const float* Wih1, const float* Whh1,
                 const float* bih1, const float* bhh1,
                 const float* fc1w, const float* fc1b,
                 const float* convw, const float* convb,
                 const float* fc2w, const float* fc2b,
                 const float* fc3w, const float* fc3b,
                 const float* gparam, const float* eattr,
                 float* P) {
    int tid = blockIdx.x * blockDim.x + threadIdx.x;
    int stride = gridDim.x * blockDim.x;
    // L0I [grp][c][j8][g]
    for (int idx = tid; idx < 1280; idx += stride) {
        int g = idx & 3, j8 = (idx >> 2) & 7, rest = idx >> 5;
        int c = rest % 10, grp = rest / 10;
        P[OFF_L0I + idx] = Wih0[(g * 32 + grp * 8 + j8) * 10 + c];
    }
    // H-type [grp][k][j8][g]
    for (int idx = tid; idx < 4096; idx += stride) {
        int g = idx & 3, j8 = (idx >> 2) & 7, rest = idx >> 5;
        int k = rest & 31, grp = rest >> 5;
        int row = (g * 32 + grp * 8 + j8) * 32 + k;
        P[OFF_L0H + idx] = Whh0[row];
        P[OFF_L1I + idx] = Wih1[row];
        P[OFF_L1H + idx] = Whh1[row];
    }
    for (int idx = tid; idx < 128; idx += stride) {
        int g = idx & 3, j = idx >> 2;
        P[OFF_B0 + idx] = bih0[g * 32 + j] + bhh0[g * 32 + j];
        P[OFF_B1 + idx] = bih1[g * 32 + j] + bhh1[g * 32 + j];
    }
    // fc1 k-major [k][ch]
    for (int idx = tid; idx < 2048; idx += stride) {
        int ch = idx & 63, k = idx >> 6;
        P[OFF_FC1W + idx] = fc1w[ch * 32 + k];
    }
    for (int i = tid; i < 64; i += stride) P[OFF_FC1B + i] = fc1b[i];
    // conv [k][co2][ci] float2 (R8 layout)
    for (int idx = tid; idx < 16384; idx += stride) {
        int k = idx >> 12, r = idx & 4095, e = r >> 1, h = r & 1;
        int co2 = e >> 6, ci = e & 63;
        P[OFF_CWT2 + idx] = convw[k * 4096 + ci * 64 + (2 * co2 + h)];
    }
    for (int i = tid; i < 256; i += stride) P[OFF_CB + i] = convb[i];
    for (int idx = tid; idx < 2048; idx += stride) {
        int e = idx >> 1, h = idx & 1, m2 = e >> 6, ch = e & 63;
        P[OFF_FC2W2 + idx] = fc2w[(2 * m2 + h) * 64 + ch];
    }
    for (int i = tid; i < 32;  i += stride) P[OFF_FC2B + i] = fc2b[i];
    // fc3 [oc2][m2] float4
    for (int idx = tid; idx < 320; idx += stride) {
        int q = idx & 3, e = idx >> 2, oc2 = e >> 4, m2 = e & 15;
        int oc = 2 * oc2 + (q & 1), m = 2 * m2 + (q >> 1);
        P[OFF_FC3W4 + idx] = fc3w[oc * 32 + m];
    }
    for (int i = tid; i < 10; i += stride) P[OFF_FC3B + i] = fc3b[i];
    for (int idx = tid; idx < 8; idx += stride) {
        int k = idx >> 1;
        float g = gparam[k];
        float denom = g * g + 1e-8f;
        float a = (idx & 1) ? eattr[0] : eattr[STRAIGHT_ATTR_IDX];
        P[OFF_GW + idx] = __expf(-(a * a) / denom);
    }
}

// ---------------- LSTM: 128 thr, 1 px/lane, FULLY UNROLLED, all state in registers ----------------
// No LDS at all: h/c state is per-lane, and with every loop unrolled all array
// indices are static -> registers. Weights stream on the scalar pipe (uniform
// 32-float rows, statically addressed -> compiler batches s_load_dwordx16 with
// long prefetch distance). t-loop rolled (body ~14k insts, streams through I$).
__global__ __launch_bounds__(128, 1)
void lstm_fc1_kernel(const float* __restrict__ x,
                     const float* __restrict__ P,
                     float* __restrict__ feats) {
    int tid = threadIdx.x;
    int n = blockIdx.x * 128 + tid;
    int b = n >> 16;
    int pix = n & (NPIX - 1);
    const float* xb = x + (size_t)b * TT * CC * NPIX + pix;

    float h0[HH], h1[HH], c0[HH], c1[HH], hn[HH];
#pragma unroll
    for (int j = 0; j < HH; j++) { h0[j] = 0.f; h1[j] = 0.f; c0[j] = 0.f; c1[j] = 0.f; }

#pragma unroll 1
    for (int t = 0; t < TT; t++) {
        float xt[CC];
#pragma unroll
        for (int c = 0; c < CC; c++) xt[c] = xb[(size_t)(t * CC + c) * NPIX];

        // ---- layer 0 ----
#pragma unroll
        for (int grp = 0; grp < 4; grp++) {
            float z[32];
#pragma unroll
            for (int e = 0; e < 32; e++) z[e] = P[OFF_B0 + grp * 32 + e];
#pragma unroll
            for (int c = 0; c < CC; c++) {
                const float* wr = P + OFF_L0I + (grp * 10 + c) * 32;
#pragma unroll
                for (int e = 0; e < 32; e++) z[e] = __builtin_fmaf(wr[e], xt[c], z[e]);
            }
#pragma unroll
            for (int k = 0; k < HH; k++) {
                const float* wr = P + OFF_L0H + (grp * 32 + k) * 32;
#pragma unroll
                for (int e = 0; e < 32; e++) z[e] = __builtin_fmaf(wr[e], h0[k], z[e]);
            }
#pragma unroll
            for (int j8 = 0; j8 < 8; j8++) {
                int j = grp * 8 + j8;
                float zi = z[j8 * 4 + 0], zf = z[j8 * 4 + 1];
                float zg = z[j8 * 4 + 2], zo = z[j8 * 4 + 3];
                float cn = sigf(zf) * c0[j] + sigf(zi) * tanhf_(zg);
                c0[j] = cn;
                hn[j] = sigf(zo) * tanhf_(cn);
            }
        }
#pragma unroll
        for (int j = 0; j < HH; j++) h0[j] = hn[j];

        // ---- layer 1 ----
#pragma unroll
        for (int grp = 0; grp < 4; grp++) {
            float z[32];
#pragma unroll
            for (int e = 0; e < 32; e++) z[e] = P[OFF_B1 + grp * 32 + e];
#pragma unroll
            for (int k = 0; k < HH; k++) {
                const float* wr = P + OFF_L1I + (grp * 32 + k) * 32;
#pragma unroll
                for (int e = 0; e < 32; e++) z[e] = __builtin_fmaf(wr[e], h0[k], z[e]);
            }
#pragma unroll
            for (int k = 0; k < HH; k++) {
                const float* wr = P + OFF_L1H + (grp * 32 + k) * 32;
#pragma unroll
                for (int e = 0; e < 32; e++) z[e] = __builtin_fmaf(wr[e], h1[k], z[e]);
            }
#pragma unroll
            for (int j8 = 0; j8 < 8; j8++) {
                int j = grp * 8 + j8;
                float zi = z[j8 * 4 + 0], zf = z[j8 * 4 + 1];
                float zg = z[j8 * 4 + 2], zo = z[j8 * 4 + 3];
                float cn = sigf(zf) * c1[j] + sigf(zi) * tanhf_(zg);
                c1[j] = cn;
                hn[j] = sigf(zo) * tanhf_(cn);
            }
        }
#pragma unroll
        for (int j = 0; j < HH; j++) h1[j] = hn[j];
    }

    // ---- fc1 + relu (k-major scalar weights, static) ----
    float f[WIDTH];
#pragma unroll
    for (int ch = 0; ch < WIDTH; ch++) f[ch] = P[OFF_FC1B + ch];
#pragma unroll
    for (int k = 0; k < HH; k++) {
        const float* wr = P + OFF_FC1W + k * 64;
#pragma unroll
        for (int ch = 0; ch < WIDTH; ch++)
            f[ch] = __builtin_fmaf(wr[ch], h1[k], f[ch]);
    }
    float* fb = feats + (size_t)b * WIDTH * NPIX + pix;
#pragma unroll
    for (int ch = 0; ch < WIDTH; ch++)
        fb[(size_t)ch * NPIX] = fmaxf(f[ch], 0.f);
}

// ---------------- fused conv layer (R8-proven: 256 thr, 1 px/lane, LDS weights) ----------------
__global__ __launch_bounds__(256, 1)
void conv_fused_kernel(const float* __restrict__ Fin, float* __restrict__ Fout,
                       const float* __restrict__ P, int k) {
    __shared__ float4 CW[1024];   // [co2][ci2]
    __shared__ float  CB[64];
    {
        const float4* src = (const float4*)(P + OFF_CWT2 + k * 4096);
        for (int i = threadIdx.x; i < 1024; i += 256) CW[i] = src[i];
        if (threadIdx.x < 64) CB[threadIdx.x] = P[OFF_CB + k * 64 + threadIdx.x];
    }
    __syncthreads();

    int n = blockIdx.x * 256 + threadIdx.x;
    int b = n >> 16;
    int pix = n & (NPIX - 1);
    int i = pix >> 8, j = pix & 255;
    float wstr = P[OFF_GW + 2 * k], wdiag = P[OFF_GW + 2 * k + 1];
    float fu = (i > 0) ? wstr : 0.f, fd = (i < 255) ? wstr : 0.f;
    float fl = (j > 0) ? wstr : 0.f, fr = (j < 255) ? wstr : 0.f;
    float ful = (i > 0 && j > 0) ? wdiag : 0.f, fur = (i > 0 && j < 255) ? wdiag : 0.f;
    float fdl = (i < 255 && j > 0) ? wdiag : 0.f, fdr = (i < 255 && j < 255) ? wdiag : 0.f;

    const float* fb = Fin + (size_t)b * WIDTH * NPIX + pix;
    float u[WIDTH];
#pragma unroll
    for (int ch = 0; ch < WIDTH; ch++) {
        const float* yc = fb + (size_t)ch * NPIX;
        float v = yc[0];
        v += fu * yc[-256] + fd * yc[256] + fl * yc[-1] + fr * yc[1];
        v += ful * yc[-257] + fur * yc[-255] + fdl * yc[255] + fdr * yc[257];
        u[ch] = v;
    }

    float* ob = Fout + (size_t)b * WIDTH * NPIX + pix;
#pragma unroll 1
    for (int co2 = 0; co2 < 32; co2++) {
        float ax = CB[2 * co2], ay = CB[2 * co2 + 1];
        const float4* wv = CW + co2 * 32;
#pragma unroll
        for (int ci2 = 0; ci2 < 32; ci2++) {
            float4 q = wv[ci2];
            float a0 = u[2 * ci2], a1 = u[2 * ci2 + 1];
            ax = __builtin_fmaf(q.x, a0, ax); ax = __builtin_fmaf(q.z, a1, ax);
            ay = __builtin_fmaf(q.y, a0, ay); ay = __builtin_fmaf(q.w, a1, ay);
        }
        ob[(size_t)(2 * co2) * NPIX]     = fmaxf(ax, 0.f);
        ob[(size_t)(2 * co2 + 1) * NPIX] = fmaxf(ay, 0.f);
    }
}

// ---------------- last conv (no relu) + fc2/fc3 head (R8-proven) ----------------
__global__ __launch_bounds__(256, 1)
void conv_head_kernel(const float* __restrict__ Fin, const float* __restrict__ P,
                      float* __restrict__ out) {
    const int k = 3;
    __shared__ float4 CW3[1024];
    __shared__ float  CB3[64];
    __shared__ float4 F2W[512];
    __shared__ float  F2B[32];
    __shared__ float4 F3W[80];
    __shared__ float  F3B[12];
    {
        const float4* s1 = (const float4*)(P + OFF_CWT2 + k * 4096);
        for (int i = threadIdx.x; i < 1024; i += 256) CW3[i] = s1[i];
        const float4* s2 = (const float4*)(P + OFF_FC2W2);
        for (int i = threadIdx.x; i < 512; i += 256) F2W[i] = s2[i];
        const float4* s3 = (const float4*)(P + OFF_FC3W4);
        if (threadIdx.x < 80) F3W[threadIdx.x] = s3[threadIdx.x];
        if (threadIdx.x < 64) CB3[threadIdx.x] = P[OFF_CB + k * 64 + threadIdx.x];
        if (threadIdx.x < 32) F2B[threadIdx.x] = P[OFF_FC2B + threadIdx.x];
        if (threadIdx.x < 10) F3B[threadIdx.x] = P[OFF_FC3B + threadIdx.x];
    }
    __syncthreads();

    int n = blockIdx.x * 256 + threadIdx.x;
    int b = n >> 16;
    int pix = n & (NPIX - 1);
    int i = pix >> 8, j = pix & 255;
    float wstr = P[OFF_GW + 2 * k], wdiag = P[OFF_GW + 2 * k + 1];
    float fu = (i > 0) ? wstr : 0.f, fd = (i < 255) ? wstr : 0.f;
    float fl = (j > 0) ? wstr : 0.f, fr = (j < 255) ? wstr : 0.f;
    float ful = (i > 0 && j > 0) ? wdiag : 0.f, fur = (i > 0 && j < 255) ? wdiag : 0.f;
    float fdl = (i < 255 && j > 0) ? wdiag : 0.f, fdr = (i < 255 && j < 255) ? wdiag : 0.f;

    const float* fb = Fin + (size_t)b * WIDTH * NPIX + pix;
    float u[WIDTH];
#pragma unroll
    for (int ch = 0; ch < WIDTH; ch++) {
        const float* yc = fb + (size_t)ch * NPIX;
        float v = yc[0];
        v += fu * yc[-256] + fd * yc[256] + fl * yc[-1] + fr * yc[1];
        v += ful * yc[-257] + fur * yc[-255] + fdl * yc[255] + fdr * yc[257];
        u[ch] = v;
    }

    float f[WIDTH];
#pragma unroll
    for (int co2 = 0; co2 < 32; co2++) {
        float ax = CB3[2 * co2], ay = CB3[2 * co2 + 1];
        const float4* wv = CW3 + co2 * 32;
#pragma unroll
        for (int ci2 = 0; ci2 < 32; ci2++) {
            float4 q = wv[ci2];
            float a0 = u[2 * ci2], a1 = u[2 * ci2 + 1];
            ax = __builtin_fmaf(q.x, a0, ax); ax = __builtin_fmaf(q.z, a1, ax);
            ay = __builtin_fmaf(q.y, a0, ay); ay = __builtin_fmaf(q.w, a1, ay);
        }
        f[2 * co2] = ax; f[2 * co2 + 1] = ay;
    }

    float2 oo[5];
#pragma unroll
    for (int oc2 = 0; oc2 < 5; oc2++) oo[oc2] = make_float2(F3B[2 * oc2], F3B[2 * oc2 + 1]);
#pragma unroll 1
    for (int m2 = 0; m2 < 16; m2++) {
        float ax = F2B[2 * m2], ay = F2B[2 * m2 + 1];
        const float4* wv = F2W + m2 * 32;
#pragma unroll
        for (int ch2 = 0; ch2 < 32; ch2++) {
            float4 q = wv[ch2];
            ax = __builtin_fmaf(q.x, f[2 * ch2], ax); ax = __builtin_fmaf(q.z, f[2 * ch2 + 1], ax);
            ay = __builtin_fmaf(q.y, f[2 * ch2], ay); ay = __builtin_fmaf(q.w, f[2 * ch2 + 1], ay);
        }
        ax = fmaxf(ax, 0.f); ay = fmaxf(ay, 0.f);
#pragma unroll
        for (int oc2 = 0; oc2 < 5; oc2++) {
            float4 q = F3W[oc2 * 16 + m2];
            oo[oc2].x += q.x * ax + q.z * ay;
            oo[oc2].y += q.y * ax + q.w * ay;
        }
    }
    float* ob = out + (size_t)b * OUTC * NPIX + pix;
#pragma unroll
    for (int oc2 = 0; oc2 < 5; oc2++) {
        ob[(size_t)(2 * oc2) * NPIX]     = oo[oc2].x;
        ob[(size_t)(2 * oc2 + 1) * NPIX] = oo[oc2].y;
    }
}

extern "C" void kernel_launch(void* const* d_in, const int* in_sizes, int n_in,
                              void* d_out, int out_size, void* d_ws, size_t ws_size,
                              hipStream_t stream) {
    const float* x     = (const float*)d_in[0];
    const float* eattr = (const float*)d_in[3];
    const float* Wih0  = (const float*)d_in[4];
    const float* Whh0  = (const float*)d_in[5];
    const float* bih0  = (const float*)d_in[6];
    const float* bhh0  = (const float*)d_in[7];
    const float* Wih1  = (const float*)d_in[8];
    const float* Whh1  = (const float*)d_in[9];
    const float* bih1  = (const float*)d_in[10];
    const float* bhh1  = (const float*)d_in[11];
    const float* fc1w  = (const float*)d_in[12];
    const float* fc1b  = (const float*)d_in[13];
    const float* convw = (const float*)d_in[14];
    const float* convb = (const float*)d_in[15];
    const float* gparam= (const float*)d_in[16];
    const float* fc2w  = (const float*)d_in[17];
    const float* fc2b  = (const float*)d_in[18];
    const float* fc3w  = (const float*)d_in[19];
    const float* fc3b  = (const float*)d_in[20];

    float* P  = (float*)d_ws;
    float* FA = P + OFF_FEATS_A;
    float* FB = P + OFF_FEATS_B;

    prep_kernel<<<64, 256, 0, stream>>>(Wih0, Whh0, bih0, bhh0, Wih1, Whh1, bih1, bhh1,
                                        fc1w, fc1b, convw, convb, fc2w, fc2b, fc3w, fc3b,
                                        gparam, eattr, P);
    lstm_fc1_kernel<<<1024, 128, 0, stream>>>(x, P, FA);
    conv_fused_kernel<<<512, 256, 0, stream>>>(FA, FB, P, 0);
    conv_fused_kernel<<<512, 256, 0, stream>>>(FB, FA, P, 1);
    conv_fused_kernel<<<512, 256, 0, stream>>>(FA, FB, P, 2);
    conv_head_kernel<<<512, 256, 0, stream>>>(FB, P, (float*)d_out);
}

// Round 11
// 1408.671 us; speedup vs baseline: 1.0865x; 1.0865x over previous
//
#include <hip/hip_runtime.h>
#include <hip/hip_bf16.h>

#define NPIX   65536
#define TT     5
#define CC     10
#define HH     32
#define WIDTH  64
#define KW     32
#define OUTC   10

// ---- workspace layout (float offsets) ----
// LSTM weights grouped by 16 units, k-major, gate-packed: [grp][k][j16][g] rows of 64
#define OFF_L0I    0        // 1280  [grp][c][j16][g]
#define OFF_L0H    1280     // 4096  [grp][k][j16][g]
#define OFF_L1I    5376     // 4096
#define OFF_L1H    9472     // 4096
#define OFF_B0     13568    // 128   [j][g]
#define OFF_B1     13696    // 128
#define OFF_FC1W   13824    // 2048  [k][ch]
#define OFF_FC1B   15872    // 64
#define OFF_CWT2   16384    // 16384 [k][co2][ci] float2  (R8 conv layout)
#define OFF_CB     32768    // 256
#define OFF_FC2W2  33024    // 2048  [m2][ch] float2
#define OFF_FC2B   35072    // 32
#define OFF_FC3W4  35104    // 320   [oc2][m2] float4
#define OFF_FC3B   35424    // 16
#define OFF_GW     35440    // 8
#define OFF_FEATS_A 36864
#define OFF_FEATS_B (36864 + 8388608)

#define STRAIGHT_ATTR_IDX (65025 * 3)

__device__ __forceinline__ float sigf(float x)  { return 1.0f / (1.0f + __expf(-x)); }
__device__ __forceinline__ float tanhf_(float x){ return 1.0f - 2.0f / (__expf(2.0f * x) + 1.0f); }
__device__ __forceinline__ float4 fma4(float4 q, float s, float4 a) {
    a.x = __builtin_fmaf(q.x, s, a.x);
    a.y = __builtin_fmaf(q.y, s, a.y);
    a.z = __builtin_fmaf(q.z, s, a.z);
    a.w = __builtin_fmaf(q.w, s, a.w);
    return a;
}

// ---------------- prep: pack params ----------------
__global__ __launch_bounds__(256, 1)
void prep_kernel(const float* Wih0, const float* Whh0,
                 const float* bih0, const float* bhh0,
                 const float* Wih1, const float* Whh1,
                 const float* bih1, const float* bhh1,
                 const float* fc1w, const float* fc1b,
                 const float* convw, const float* convb,
                 const float* fc2w, const float* fc2b,
                 const float* fc3w, const float* fc3b,
                 const float* gparam, const float* eattr,
                 float* P) {
    int tid = blockIdx.x * blockDim.x + threadIdx.x;
    int stride = gridDim.x * blockDim.x;
    // L0I [grp][c][j16][g]: idx = ((grp*10+c)*16+j16)*4+g
    for (int idx = tid; idx < 1280; idx += stride) {
        int g = idx & 3, j16 = (idx >> 2) & 15, rest = idx >> 6;
        int c = rest % 10, grp = rest / 10;
        P[OFF_L0I + idx] = Wih0[(g * 32 + grp * 16 + j16) * 10 + c];
    }
    // H-type [grp][k][j16][g]: idx = ((grp*32+k)*16+j16)*4+g
    for (int idx = tid; idx < 4096; idx += stride) {
        int g = idx & 3, j16 = (idx >> 2) & 15, rest = idx >> 6;
        int k = rest & 31, grp = rest >> 5;
        int row = (g * 32 + grp * 16 + j16) * 32 + k;
        P[OFF_L0H + idx] = Whh0[row];
        P[OFF_L1I + idx] = Wih1[row];
        P[OFF_L1H + idx] = Whh1[row];
    }
    // biases [grp][j16][g] = [j][g]
    for (int idx = tid; idx < 128; idx += stride) {
        int g = idx & 3, j = idx >> 2;
        P[OFF_B0 + idx] = bih0[g * 32 + j] + bhh0[g * 32 + j];
        P[OFF_B1 + idx] = bih1[g * 32 + j] + bhh1[g * 32 + j];
    }
    // fc1 k-major [k][ch]
    for (int idx = tid; idx < 2048; idx += stride) {
        int ch = idx & 63, k = idx >> 6;
        P[OFF_FC1W + idx] = fc1w[ch * 32 + k];
    }
    for (int i = tid; i < 64; i += stride) P[OFF_FC1B + i] = fc1b[i];
    // conv [k][co2][ci] float2 (R8 layout)
    for (int idx = tid; idx < 16384; idx += stride) {
        int k = idx >> 12, r = idx & 4095, e = r >> 1, h = r & 1;
        int co2 = e >> 6, ci = e & 63;
        P[OFF_CWT2 + idx] = convw[k * 4096 + ci * 64 + (2 * co2 + h)];
    }
    for (int i = tid; i < 256; i += stride) P[OFF_CB + i] = convb[i];
    for (int idx = tid; idx < 2048; idx += stride) {
        int e = idx >> 1, h = idx & 1, m2 = e >> 6, ch = e & 63;
        P[OFF_FC2W2 + idx] = fc2w[(2 * m2 + h) * 64 + ch];
    }
    for (int i = tid; i < 32;  i += stride) P[OFF_FC2B + i] = fc2b[i];
    // fc3 [oc2][m2] float4
    for (int idx = tid; idx < 320; idx += stride) {
        int q = idx & 3, e = idx >> 2, oc2 = e >> 4, m2 = e & 15;
        int oc = 2 * oc2 + (q & 1), m = 2 * m2 + (q >> 1);
        P[OFF_FC3W4 + idx] = fc3w[oc * 32 + m];
    }
    for (int i = tid; i < 10; i += stride) P[OFF_FC3B + i] = fc3b[i];
    for (int idx = tid; idx < 8; idx += stride) {
        int k = idx >> 1;
        float g = gparam[k];
        float denom = g * g + 1e-8f;
        float a = (idx & 1) ? eattr[0] : eattr[STRAIGHT_ATTR_IDX];
        P[OFF_GW + idx] = __expf(-(a * a) / denom);
    }
}

// ---------------- LSTM: 128 thr, 1 px/lane, 2 unit-groups of 16 ----------------
// z[16] float4 = 64 VGPR acc (R8's 128 caused AGPR shuffle; R9's 32-burst stalled
// on scalar latency). 64-FMA bursts per 64-float uniform row. h state in per-lane
// LDS columns (dynamic k index under rolled k-loop); xt in regs (c-loop unrolled).
__global__ __launch_bounds__(128, 1)
void lstm_fc1_kernel(const float* __restrict__ x,
                     const float* __restrict__ P,
                     float* __restrict__ feats) {
    __shared__ float H0[HH * 128];   // 16384 B
    __shared__ float H1[HH * 128];   // 16384 B  (32768 total)

    int tid = threadIdx.x;
    int n = blockIdx.x * 128 + tid;
    int b = n >> 16;
    int pix = n & (NPIX - 1);
    const float* xb = x + (size_t)b * TT * CC * NPIX + pix;

    float c0[HH], c1[HH], hn[HH];
#pragma unroll
    for (int j = 0; j < HH; j++) {
        c0[j] = 0.f; c1[j] = 0.f;
        H0[j * 128 + tid] = 0.f;
        H1[j * 128 + tid] = 0.f;
    }

#pragma unroll 1
    for (int t = 0; t < TT; t++) {
        float xt[CC];
#pragma unroll
        for (int c = 0; c < CC; c++) xt[c] = xb[(size_t)(t * CC + c) * NPIX];

        // ---- layer 0: 2 groups of 16 units ----
#pragma unroll
        for (int grp = 0; grp < 2; grp++) {
            float4 z[16];
#pragma unroll
            for (int j16 = 0; j16 < 16; j16++)
                z[j16] = *(const float4*)(P + OFF_B0 + grp * 64 + j16 * 4);
#pragma unroll
            for (int c = 0; c < CC; c++) {
                const float4* w4 = (const float4*)(P + OFF_L0I + (grp * 10 + c) * 64);
#pragma unroll
                for (int j16 = 0; j16 < 16; j16++) z[j16] = fma4(w4[j16], xt[c], z[j16]);
            }
#pragma unroll 1
            for (int k = 0; k < HH; k++) {
                float hv = H0[k * 128 + tid];
                const float4* w4 = (const float4*)(P + OFF_L0H + (grp * 32 + k) * 64);
#pragma unroll
                for (int j16 = 0; j16 < 16; j16++) z[j16] = fma4(w4[j16], hv, z[j16]);
            }
#pragma unroll
            for (int j16 = 0; j16 < 16; j16++) {
                int j = grp * 16 + j16;
                float cn = sigf(z[j16].y) * c0[j] + sigf(z[j16].x) * tanhf_(z[j16].z);
                c0[j] = cn;
                hn[j] = sigf(z[j16].w) * tanhf_(cn);
            }
        }
#pragma unroll
        for (int j = 0; j < HH; j++) H0[j * 128 + tid] = hn[j];

        // ---- layer 1 ----
#pragma unroll
        for (int grp = 0; grp < 2; grp++) {
            float4 z[16];
#pragma unroll
            for (int j16 = 0; j16 < 16; j16++)
                z[j16] = *(const float4*)(P + OFF_B1 + grp * 64 + j16 * 4);
#pragma unroll 1
            for (int k = 0; k < HH; k++) {
                float hv = H0[k * 128 + tid];
                const float4* w4 = (const float4*)(P + OFF_L1I + (grp * 32 + k) * 64);
#pragma unroll
                for (int j16 = 0; j16 < 16; j16++) z[j16] = fma4(w4[j16], hv, z[j16]);
            }
#pragma unroll 1
            for (int k = 0; k < HH; k++) {
                float hv = H1[k * 128 + tid];
                const float4* w4 = (const float4*)(P + OFF_L1H + (grp * 32 + k) * 64);
#pragma unroll
                for (int j16 = 0; j16 < 16; j16++) z[j16] = fma4(w4[j16], hv, z[j16]);
            }
#pragma unroll
            for (int j16 = 0; j16 < 16; j16++) {
                int j = grp * 16 + j16;
                float cn = sigf(z[j16].y) * c1[j] + sigf(z[j16].x) * tanhf_(z[j16].z);
                c1[j] = cn;
                hn[j] = sigf(z[j16].w) * tanhf_(cn);
            }
        }
#pragma unroll
        for (int j = 0; j < HH; j++) H1[j * 128 + tid] = hn[j];
    }

    // ---- fc1 + relu (k-major scalar weights, k rolled) ----
    float f[WIDTH];
#pragma unroll
    for (int ch = 0; ch < WIDTH; ch++) f[ch] = P[OFF_FC1B + ch];
#pragma unroll 1
    for (int k = 0; k < HH; k++) {
        float hv = H1[k * 128 + tid];
        const float* wr = P + OFF_FC1W + k * 64;
#pragma unroll
        for (int ch = 0; ch < WIDTH; ch++)
            f[ch] = __builtin_fmaf(wr[ch], hv, f[ch]);
    }
    float* fb = feats + (size_t)b * WIDTH * NPIX + pix;
#pragma unroll
    for (int ch = 0; ch < WIDTH; ch++)
        fb[(size_t)ch * NPIX] = fmaxf(f[ch], 0.f);
}

// ---------------- fused conv layer (R8-proven: 256 thr, 1 px/lane, LDS weights) ----------------
__global__ __launch_bounds__(256, 1)
void conv_fused_kernel(const float* __restrict__ Fin, float* __restrict__ Fout,
                       const float* __restrict__ P, int k) {
    __shared__ float4 CW[1024];   // [co2][ci2]
    __shared__ float  CB[64];
    {
        const float4* src = (const float4*)(P + OFF_CWT2 + k * 4096);
        for (int i = threadIdx.x; i < 1024; i += 256) CW[i] = src[i];
        if (threadIdx.x < 64) CB[threadIdx.x] = P[OFF_CB + k * 64 + threadIdx.x];
    }
    __syncthreads();

    int n = blockIdx.x * 256 + threadIdx.x;
    int b = n >> 16;
    int pix = n & (NPIX - 1);
    int i = pix >> 8, j = pix & 255;
    float wstr = P[OFF_GW + 2 * k], wdiag = P[OFF_GW + 2 * k + 1];
    float fu = (i > 0) ? wstr : 0.f, fd = (i < 255) ? wstr : 0.f;
    float fl = (j > 0) ? wstr : 0.f, fr = (j < 255) ? wstr : 0.f;
    float ful = (i > 0 && j > 0) ? wdiag : 0.f, fur = (i > 0 && j < 255) ? wdiag : 0.f;
    float fdl = (i < 255 && j > 0) ? wdiag : 0.f, fdr = (i < 255 && j < 255) ? wdiag : 0.f;

    const float* fb = Fin + (size_t)b * WIDTH * NPIX + pix;
    float u[WIDTH];
#pragma unroll
    for (int ch = 0; ch < WIDTH; ch++) {
        const float* yc = fb + (size_t)ch * NPIX;
        float v = yc[0];
        v += fu * yc[-256] + fd * yc[256] + fl * yc[-1] + fr * yc[1];
        v += ful * yc[-257] + fur * yc[-255] + fdl * yc[255] + fdr * yc[257];
        u[ch] = v;
    }

    float* ob = Fout + (size_t)b * WIDTH * NPIX + pix;
#pragma unroll 1
    for (int co2 = 0; co2 < 32; co2++) {
        float ax = CB[2 * co2], ay = CB[2 * co2 + 1];
        const float4* wv = CW + co2 * 32;
#pragma unroll
        for (int ci2 = 0; ci2 < 32; ci2++) {
            float4 q = wv[ci2];
            float a0 = u[2 * ci2], a1 = u[2 * ci2 + 1];
            ax = __builtin_fmaf(q.x, a0, ax); ax = __builtin_fmaf(q.z, a1, ax);
            ay = __builtin_fmaf(q.y, a0, ay); ay = __builtin_fmaf(q.w, a1, ay);
        }
        ob[(size_t)(2 * co2) * NPIX]     = fmaxf(ax, 0.f);
        ob[(size_t)(2 * co2 + 1) * NPIX] = fmaxf(ay, 0.f);
    }
}

// ---------------- last conv (no relu) + fc2/fc3 head (R8-proven) ----------------
__global__ __launch_bounds__(256, 1)
void conv_head_kernel(const float* __restrict__ Fin, const float* __restrict__ P,
                      float* __restrict__ out) {
    const int k = 3;
    __shared__ float4 CW3[1024];
    __shared__ float  CB3[64];
    __shared__ float4 F2W[512];
    __shared__ float  F2B[32];
    __shared__ float4 F3W[80];
    __shared__ float  F3B[12];
    {
        const float4* s1 = (const float4*)(P + OFF_CWT2 + k * 4096);
        for (int i = threadIdx.x; i < 1024; i += 256) CW3[i] = s1[i];
        const float4* s2 = (const float4*)(P + OFF_FC2W2);
        for (int i = threadIdx.x; i < 512; i += 256) F2W[i] = s2[i];
        const float4* s3 = (const float4*)(P + OFF_FC3W4);
        if (threadIdx.x < 80) F3W[threadIdx.x] = s3[threadIdx.x];
        if (threadIdx.x < 64) CB3[threadIdx.x] = P[OFF_CB + k * 64 + threadIdx.x];
        if (threadIdx.x < 32) F2B[threadIdx.x] = P[OFF_FC2B + threadIdx.x];
        if (threadIdx.x < 10) F3B[threadIdx.x] = P[OFF_FC3B + threadIdx.x];
    }
    __syncthreads();

    int n = blockIdx.x * 256 + threadIdx.x;
    int b = n >> 16;
    int pix = n & (NPIX - 1);
    int i = pix >> 8, j = pix & 255;
    float wstr = P[OFF_GW + 2 * k], wdiag = P[OFF_GW + 2 * k + 1];
    float fu = (i > 0) ? wstr : 0.f, fd = (i < 255) ? wstr : 0.f;
    float fl = (j > 0) ? wstr : 0.f, fr = (j < 255) ? wstr : 0.f;
    float ful = (i > 0 && j > 0) ? wdiag : 0.f, fur = (i > 0 && j < 255) ? wdiag : 0.f;
    float fdl = (i < 255 && j > 0) ? wdiag : 0.f, fdr = (i < 255 && j < 255) ? wdiag : 0.f;

    const float* fb = Fin + (size_t)b * WIDTH * NPIX + pix;
    float u[WIDTH];
#pragma unroll
    for (int ch = 0; ch < WIDTH; ch++) {
        const float* yc = fb + (size_t)ch * NPIX;
        float v = yc[0];
        v += fu * yc[-256] + fd * yc[256] + fl * yc[-1] + fr * yc[1];
        v += ful * yc[-257] + fur * yc[-255] + fdl * yc[255] + fdr * yc[257];
        u[ch] = v;
    }

    float f[WIDTH];
#pragma unroll
    for (int co2 = 0; co2 < 32; co2++) {
        float ax = CB3[2 * co2], ay = CB3[2 * co2 + 1];
        const float4* wv = CW3 + co2 * 32;
#pragma unroll
        for (int ci2 = 0; ci2 < 32; ci2++) {
            float4 q = wv[ci2];
            float a0 = u[2 * ci2], a1 = u[2 * ci2 + 1];
            ax = __builtin_fmaf(q.x, a0, ax); ax = __builtin_fmaf(q.z, a1, ax);
            ay = __builtin_fmaf(q.y, a0, ay); ay = __builtin_fmaf(q.w, a1, ay);
        }
        f[2 * co2] = ax; f[2 * co2 + 1] = ay;
    }

    float2 oo[5];
#pragma unroll
    for (int oc2 = 0; oc2 < 5; oc2++) oo[oc2] = make_float2(F3B[2 * oc2], F3B[2 * oc2 + 1]);
#pragma unroll 1
    for (int m2 = 0; m2 < 16; m2++) {
        float ax = F2B[2 * m2], ay = F2B[2 * m2 + 1];
        const float4* wv = F2W + m2 * 32;
#pragma unroll
        for (int ch2 = 0; ch2 < 32; ch2++) {
            float4 q = wv[ch2];
            ax = __builtin_fmaf(q.x, f[2 * ch2], ax); ax = __builtin_fmaf(q.z, f[2 * ch2 + 1], ax);
            ay = __builtin_fmaf(q.y, f[2 * ch2], ay); ay = __builtin_fmaf(q.w, f[2 * ch2 + 1], ay);
        }
        ax = fmaxf(ax, 0.f); ay = fmaxf(ay, 0.f);
#pragma unroll
        for (int oc2 = 0; oc2 < 5; oc2++) {
            float4 q = F3W[oc2 * 16 + m2];
            oo[oc2].x += q.x * ax + q.z * ay;
            oo[oc2].y += q.y * ax + q.w * ay;
        }
    }
    float* ob = out + (size_t)b * OUTC * NPIX + pix;
#pragma unroll
    for (int oc2 = 0; oc2 < 5; oc2++) {
        ob[(size_t)(2 * oc2) * NPIX]     = oo[oc2].x;
        ob[(size_t)(2 * oc2 + 1) * NPIX] = oo[oc2].y;
    }
}

extern "C" void kernel_launch(void* const* d_in, const int* in_sizes, int n_in,
                              void* d_out, int out_size, void* d_ws, size_t ws_size,
                              hipStream_t stream) {
    const float* x     = (const float*)d_in[0];
    const float* eattr = (const float*)d_in[3];
    const float* Wih0  = (const float*)d_in[4];
    const float* Whh0  = (const float*)d_in[5];
    const float* bih0  = (const float*)d_in[6];
    const float* bhh0  = (const float*)d_in[7];
    const float* Wih1  = (const float*)d_in[8];
    const float* Whh1  = (const float*)d_in[9];
    const float* bih1  = (const float*)d_in[10];
    const float* bhh1  = (const float*)d_in[11];
    const float* fc1w  = (const float*)d_in[12];
    const float* fc1b  = (const float*)d_in[13];
    const float* convw = (const float*)d_in[14];
    const float* convb = (const float*)d_in[15];
    const float* gparam= (const float*)d_in[16];
    const float* fc2w  = (const float*)d_in[17];
    const float* fc2b  = (const float*)d_in[18];
    const float* fc3w  = (const float*)d_in[19];
    const float* fc3b  = (const float*)d_in[20];

    float* P  = (float*)d_ws;
    float* FA = P + OFF_FEATS_A;
    float* FB = P + OFF_FEATS_B;

    prep_kernel<<<64, 256, 0, stream>>>(Wih0, Whh0, bih0, bhh0, Wih1, Whh1, bih1, bhh1,
                                        fc1w, fc1b, convw, convb, fc2w, fc2b, fc3w, fc3b,
                                        gparam, eattr, P);
    lstm_fc1_kernel<<<1024, 128, 0, stream>>>(x, P, FA);
    conv_fused_kernel<<<512, 256, 0, stream>>>(FA, FB, P, 0);
    conv_fused_kernel<<<512, 256, 0, stream>>>(FB, FA, P, 1);
    conv_fused_kernel<<<512, 256, 0, stream>>>(FA, FB, P, 2);
    conv_head_kernel<<<512, 256, 0, stream>>>(FB, P, (float*)d_out);
}

// Round 12
// 638.893 us; speedup vs baseline: 2.3955x; 2.2049x over previous
//
#include <hip/hip_runtime.h>
#include <hip/hip_bf16.h>

#define NPIX   65536
#define TT     5
#define CC     10
#define HH     32
#define WIDTH  64
#define KW     32
#define OUTC   10

// ---- workspace layout (float offsets) ----
// LSTM weights k-major gate-packed: [k][j][g], g=(i,f,g,o)  -- R8-proven layout.
// Weight reads MUST stay scalar-float (wr[e]) -- float4 casts break LLVM's
// uniformity analysis and turn s_load into per-lane global_load (R11: 3.1x regress).
#define OFF_L0I    0        // 1280  [c][j][g]
#define OFF_L0H    1280     // 4096  [k][j][g]
#define OFF_L1I    5376     // 4096
#define OFF_L1H    9472     // 4096
#define OFF_B0     13568    // 128   [j][g]
#define OFF_B1     13696    // 128
#define OFF_FC1W   13824    // 2048  [k][ch]
#define OFF_FC1B   15872    // 64
#define OFF_CWT2   16384    // 16384 [k][co2][ci] float2 (conv, LDS-staged)
#define OFF_CB     32768    // 256
#define OFF_FC2W2  33024    // 2048  [m2][ch] float2
#define OFF_FC2B   35072    // 32
#define OFF_FC3W4  35104    // 320   [oc2][m2] float4
#define OFF_FC3B   35424    // 16
#define OFF_GW     35440    // 8
#define OFF_FEATS_A 36864
#define OFF_FEATS_B (36864 + 8388608)

#define STRAIGHT_ATTR_IDX (65025 * 3)

__device__ __forceinline__ float sigf(float x)  { return 1.0f / (1.0f + __expf(-x)); }
__device__ __forceinline__ float tanhf_(float x){ return 1.0f - 2.0f / (__expf(2.0f * x) + 1.0f); }

// ---------------- prep: pack params ----------------
__global__ __launch_bounds__(256, 1)
void prep_kernel(const float* Wih0, const float* Whh0,
                 const float* bih0, const float* bhh0,
                 const float* Wih1, const float* Whh1,
                 const float* bih1, const float* bhh1,
                 const float* fc1w, const float* fc1b,
                 const float* convw, const float* convb,
                 const float* fc2w, const float* fc2b,
                 const float* fc3w, const float* fc3b,
                 const float* gparam, const float* eattr,
                 float* P) {
    int tid = blockIdx.x * blockDim.x + threadIdx.x;
    int stride = gridDim.x * blockDim.x;
    // LSTM k-major: [k][j][g] <- W[(g*32+j)*K + k]
    for (int idx = tid; idx < 1280; idx += stride) {
        int g = idx & 3, j = (idx >> 2) & 31, c = idx >> 7;
        P[OFF_L0I + idx] = Wih0[(g * 32 + j) * 10 + c];
    }
    for (int idx = tid; idx < 4096; idx += stride) {
        int g = idx & 3, j = (idx >> 2) & 31, k = idx >> 7;
        P[OFF_L0H + idx] = Whh0[(g * 32 + j) * 32 + k];
        P[OFF_L1I + idx] = Wih1[(g * 32 + j) * 32 + k];
        P[OFF_L1H + idx] = Whh1[(g * 32 + j) * 32 + k];
    }
    for (int idx = tid; idx < 128; idx += stride) {
        int g = idx & 3, j = idx >> 2;
        P[OFF_B0 + idx] = bih0[g * 32 + j] + bhh0[g * 32 + j];
        P[OFF_B1 + idx] = bih1[g * 32 + j] + bhh1[g * 32 + j];
    }
    // fc1 k-major [k][ch]
    for (int idx = tid; idx < 2048; idx += stride) {
        int ch = idx & 63, k = idx >> 6;
        P[OFF_FC1W + idx] = fc1w[ch * 32 + k];
    }
    for (int i = tid; i < 64; i += stride) P[OFF_FC1B + i] = fc1b[i];
    // conv [k][co2][ci] float2
    for (int idx = tid; idx < 16384; idx += stride) {
        int k = idx >> 12, r = idx & 4095, e = r >> 1, h = r & 1;
        int co2 = e >> 6, ci = e & 63;
        P[OFF_CWT2 + idx] = convw[k * 4096 + ci * 64 + (2 * co2 + h)];
    }
    for (int i = tid; i < 256; i += stride) P[OFF_CB + i] = convb[i];
    for (int idx = tid; idx < 2048; idx += stride) {
        int e = idx >> 1, h = idx & 1, m2 = e >> 6, ch = e & 63;
        P[OFF_FC2W2 + idx] = fc2w[(2 * m2 + h) * 64 + ch];
    }
    for (int i = tid; i < 32;  i += stride) P[OFF_FC2B + i] = fc2b[i];
    // fc3 [oc2][m2] float4
    for (int idx = tid; idx < 320; idx += stride) {
        int q = idx & 3, e = idx >> 2, oc2 = e >> 4, m2 = e & 15;
        int oc = 2 * oc2 + (q & 1), m = 2 * m2 + (q >> 1);
        P[OFF_FC3W4 + idx] = fc3w[oc * 32 + m];
    }
    for (int i = tid; i < 10; i += stride) P[OFF_FC3B + i] = fc3b[i];
    for (int idx = tid; idx < 8; idx += stride) {
        int k = idx >> 1;
        float g = gparam[k];
        float denom = g * g + 1e-8f;
        float a = (idx & 1) ? eattr[0] : eattr[STRAIGHT_ATTR_IDX];
        P[OFF_GW + idx] = __expf(-(a * a) / denom);
    }
}

// ---------------- LSTM: 128 thr, 1 px/lane, whole LSTM per lane (R8, best measured) ----------------
// Weights wave-uniform -> scalar s_load stream (k-major rows of 128 floats, read as
// SCALAR floats). h/x state in per-lane LDS columns (own column only -> no barriers).
// c in static registers; z gate accumulator handled by compiler (partial AGPR).
__global__ __launch_bounds__(128, 1)
void lstm_fc1_kernel(const float* __restrict__ x,
                     const float* __restrict__ P,
                     float* __restrict__ feats) {
    __shared__ float XS[CC * 128];   // 5120 B
    __shared__ float H0[HH * 128];   // 16384 B
    __shared__ float H1[HH * 128];   // 16384 B  (total 37888)

    int tid = threadIdx.x;
    int n = blockIdx.x * 128 + tid;
    int b = n >> 16;
    int pix = n & (NPIX - 1);
    const float* xb = x + (size_t)b * TT * CC * NPIX + pix;

    float4 z[HH];
    float c0[HH], c1[HH];
#pragma unroll
    for (int j = 0; j < HH; j++) {
        c0[j] = 0.f; c1[j] = 0.f;
        H0[j * 128 + tid] = 0.f;
        H1[j * 128 + tid] = 0.f;
    }

#pragma unroll 1
    for (int t = 0; t < TT; t++) {
#pragma unroll
        for (int c = 0; c < CC; c++)
            XS[c * 128 + tid] = xb[(size_t)(t * CC + c) * NPIX];

        // ---- layer 0 ----
#pragma unroll
        for (int j = 0; j < HH; j++) z[j] = *(const float4*)(P + OFF_B0 + 4 * j);
#pragma unroll 1
        for (int c = 0; c < CC; c++) {
            float xv = XS[c * 128 + tid];
            const float* wr = P + OFF_L0I + c * 128;
#pragma unroll
            for (int j = 0; j < HH; j++) {
                z[j].x = __builtin_fmaf(wr[4 * j + 0], xv, z[j].x);
                z[j].y = __builtin_fmaf(wr[4 * j + 1], xv, z[j].y);
                z[j].z = __builtin_fmaf(wr[4 * j + 2], xv, z[j].z);
                z[j].w = __builtin_fmaf(wr[4 * j + 3], xv, z[j].w);
            }
        }
#pragma unroll 1
        for (int k = 0; k < HH; k++) {
            float hv = H0[k * 128 + tid];
            const float* wr = P + OFF_L0H + k * 128;
#pragma unroll
            for (int j = 0; j < HH; j++) {
                z[j].x = __builtin_fmaf(wr[4 * j + 0], hv, z[j].x);
                z[j].y = __builtin_fmaf(wr[4 * j + 1], hv, z[j].y);
                z[j].z = __builtin_fmaf(wr[4 * j + 2], hv, z[j].z);
                z[j].w = __builtin_fmaf(wr[4 * j + 3], hv, z[j].w);
            }
        }
#pragma unroll
        for (int j = 0; j < HH; j++) {
            float cn = sigf(z[j].y) * c0[j] + sigf(z[j].x) * tanhf_(z[j].z);
            c0[j] = cn;
            H0[j * 128 + tid] = sigf(z[j].w) * tanhf_(cn);   // own column only
        }

        // ---- layer 1 ----
#pragma unroll
        for (int j = 0; j < HH; j++) z[j] = *(const float4*)(P + OFF_B1 + 4 * j);
#pragma unroll 1
        for (int k = 0; k < HH; k++) {
            float hv = H0[k * 128 + tid];
            const float* wr = P + OFF_L1I + k * 128;
#pragma unroll
            for (int j = 0; j < HH; j++) {
                z[j].x = __builtin_fmaf(wr[4 * j + 0], hv, z[j].x);
                z[j].y = __builtin_fmaf(wr[4 * j + 1], hv, z[j].y);
                z[j].z = __builtin_fmaf(wr[4 * j + 2], hv, z[j].z);
                z[j].w = __builtin_fmaf(wr[4 * j + 3], hv, z[j].w);
            }
        }
#pragma unroll 1
        for (int k = 0; k < HH; k++) {
            float hv = H1[k * 128 + tid];           // old h1 (updated after loop)
            const float* wr = P + OFF_L1H + k * 128;
#pragma unroll
            for (int j = 0; j < HH; j++) {
                z[j].x = __builtin_fmaf(wr[4 * j + 0], hv, z[j].x);
                z[j].y = __builtin_fmaf(wr[4 * j + 1], hv, z[j].y);
                z[j].z = __builtin_fmaf(wr[4 * j + 2], hv, z[j].z);
                z[j].w = __builtin_fmaf(wr[4 * j + 3], hv, z[j].w);
            }
        }
#pragma unroll
        for (int j = 0; j < HH; j++) {
            float cn = sigf(z[j].y) * c1[j] + sigf(z[j].x) * tanhf_(z[j].z);
            c1[j] = cn;
            H1[j * 128 + tid] = sigf(z[j].w) * tanhf_(cn);
        }
    }

    // ---- fc1 + relu (k-major scalar weights) ----
    float f[WIDTH];
#pragma unroll
    for (int ch = 0; ch < WIDTH; ch++) f[ch] = P[OFF_FC1B + ch];
#pragma unroll 1
    for (int k = 0; k < HH; k++) {
        float hv = H1[k * 128 + tid];
        const float* wr = P + OFF_FC1W + k * 64;
#pragma unroll
        for (int ch = 0; ch < WIDTH; ch++)
            f[ch] = __builtin_fmaf(wr[ch], hv, f[ch]);
    }
    float* fb = feats + (size_t)b * WIDTH * NPIX + pix;
#pragma unroll
    for (int ch = 0; ch < WIDTH; ch++)
        fb[(size_t)ch * NPIX] = fmaxf(f[ch], 0.f);
}

// ---------------- fused conv layer (R8-proven: 256 thr, 1 px/lane, LDS weights) ----------------
__global__ __launch_bounds__(256, 1)
void conv_fused_kernel(const float* __restrict__ Fin, float* __restrict__ Fout,
                       const float* __restrict__ P, int k) {
    __shared__ float4 CW[1024];   // [co2][ci2]
    __shared__ float  CB[64];
    {
        const float4* src = (const float4*)(P + OFF_CWT2 + k * 4096);
        for (int i = threadIdx.x; i < 1024; i += 256) CW[i] = src[i];
        if (threadIdx.x < 64) CB[threadIdx.x] = P[OFF_CB + k * 64 + threadIdx.x];
    }
    __syncthreads();

    int n = blockIdx.x * 256 + threadIdx.x;
    int b = n >> 16;
    int pix = n & (NPIX - 1);
    int i = pix >> 8, j = pix & 255;
    float wstr = P[OFF_GW + 2 * k], wdiag = P[OFF_GW + 2 * k + 1];
    float fu = (i > 0) ? wstr : 0.f, fd = (i < 255) ? wstr : 0.f;
    float fl = (j > 0) ? wstr : 0.f, fr = (j < 255) ? wstr : 0.f;
    float ful = (i > 0 && j > 0) ? wdiag : 0.f, fur = (i > 0 && j < 255) ? wdiag : 0.f;
    float fdl = (i < 255 && j > 0) ? wdiag : 0.f, fdr = (i < 255 && j < 255) ? wdiag : 0.f;

    const float* fb = Fin + (size_t)b * WIDTH * NPIX + pix;
    float u[WIDTH];
#pragma unroll
    for (int ch = 0; ch < WIDTH; ch++) {
        const float* yc = fb + (size_t)ch * NPIX;
        float v = yc[0];
        v += fu * yc[-256] + fd * yc[256] + fl * yc[-1] + fr * yc[1];
        v += ful * yc[-257] + fur * yc[-255] + fdl * yc[255] + fdr * yc[257];
        u[ch] = v;
    }

    float* ob = Fout + (size_t)b * WIDTH * NPIX + pix;
#pragma unroll 1
    for (int co2 = 0; co2 < 32; co2++) {
        float ax = CB[2 * co2], ay = CB[2 * co2 + 1];
        const float4* wv = CW + co2 * 32;
#pragma unroll
        for (int ci2 = 0; ci2 < 32; ci2++) {
            float4 q = wv[ci2];
            float a0 = u[2 * ci2], a1 = u[2 * ci2 + 1];
            ax = __builtin_fmaf(q.x, a0, ax); ax = __builtin_fmaf(q.z, a1, ax);
            ay = __builtin_fmaf(q.y, a0, ay); ay = __builtin_fmaf(q.w, a1, ay);
        }
        ob[(size_t)(2 * co2) * NPIX]     = fmaxf(ax, 0.f);
        ob[(size_t)(2 * co2 + 1) * NPIX] = fmaxf(ay, 0.f);
    }
}

// ---------------- last conv (no relu) + fc2/fc3 head (R8-proven) ----------------
__global__ __launch_bounds__(256, 1)
void conv_head_kernel(const float* __restrict__ Fin, const float* __restrict__ P,
                      float* __restrict__ out) {
    const int k = 3;
    __shared__ float4 CW3[1024];
    __shared__ float  CB3[64];
    __shared__ float4 F2W[512];
    __shared__ float  F2B[32];
    __shared__ float4 F3W[80];
    __shared__ float  F3B[12];
    {
        const float4* s1 = (const float4*)(P + OFF_CWT2 + k * 4096);
        for (int i = threadIdx.x; i < 1024; i += 256) CW3[i] = s1[i];
        const float4* s2 = (const float4*)(P + OFF_FC2W2);
        for (int i = threadIdx.x; i < 512; i += 256) F2W[i] = s2[i];
        const float4* s3 = (const float4*)(P + OFF_FC3W4);
        if (threadIdx.x < 80) F3W[threadIdx.x] = s3[threadIdx.x];
        if (threadIdx.x < 64) CB3[threadIdx.x] = P[OFF_CB + k * 64 + threadIdx.x];
        if (threadIdx.x < 32) F2B[threadIdx.x] = P[OFF_FC2B + threadIdx.x];
        if (threadIdx.x < 10) F3B[threadIdx.x] = P[OFF_FC3B + threadIdx.x];
    }
    __syncthreads();

    int n = blockIdx.x * 256 + threadIdx.x;
    int b = n >> 16;
    int pix = n & (NPIX - 1);
    int i = pix >> 8, j = pix & 255;
    float wstr = P[OFF_GW + 2 * k], wdiag = P[OFF_GW + 2 * k + 1];
    float fu = (i > 0) ? wstr : 0.f, fd = (i < 255) ? wstr : 0.f;
    float fl = (j > 0) ? wstr : 0.f, fr = (j < 255) ? wstr : 0.f;
    float ful = (i > 0 && j > 0) ? wdiag : 0.f, fur = (i > 0 && j < 255) ? wdiag : 0.f;
    float fdl = (i < 255 && j > 0) ? wdiag : 0.f, fdr = (i < 255 && j < 255) ? wdiag : 0.f;

    const float* fb = Fin + (size_t)b * WIDTH * NPIX + pix;
    float u[WIDTH];
#pragma unroll
    for (int ch = 0; ch < WIDTH; ch++) {
        const float* yc = fb + (size_t)ch * NPIX;
        float v = yc[0];
        v += fu * yc[-256] + fd * yc[256] + fl * yc[-1] + fr * yc[1];
        v += ful * yc[-257] + fur * yc[-255] + fdl * yc[255] + fdr * yc[257];
        u[ch] = v;
    }

    float f[WIDTH];
#pragma unroll
    for (int co2 = 0; co2 < 32; co2++) {
        float ax = CB3[2 * co2], ay = CB3[2 * co2 + 1];
        const float4* wv = CW3 + co2 * 32;
#pragma unroll
        for (int ci2 = 0; ci2 < 32; ci2++) {
            float4 q = wv[ci2];
            float a0 = u[2 * ci2], a1 = u[2 * ci2 + 1];
            ax = __builtin_fmaf(q.x, a0, ax); ax = __builtin_fmaf(q.z, a1, ax);
            ay = __builtin_fmaf(q.y, a0, ay); ay = __builtin_fmaf(q.w, a1, ay);
        }
        f[2 * co2] = ax; f[2 * co2 + 1] = ay;
    }

    float2 oo[5];
#pragma unroll
    for (int oc2 = 0; oc2 < 5; oc2++) oo[oc2] = make_float2(F3B[2 * oc2], F3B[2 * oc2 + 1]);
#pragma unroll 1
    for (int m2 = 0; m2 < 16; m2++) {
        float ax = F2B[2 * m2], ay = F2B[2 * m2 + 1];
        const float4* wv = F2W + m2 * 32;
#pragma unroll
        for (int ch2 = 0; ch2 < 32; ch2++) {
            float4 q = wv[ch2];
            ax = __builtin_fmaf(q.x, f[2 * ch2], ax); ax = __builtin_fmaf(q.z, f[2 * ch2 + 1], ax);
            ay = __builtin_fmaf(q.y, f[2 * ch2], ay); ay = __builtin_fmaf(q.w, f[2 * ch2 + 1], ay);
        }
        ax = fmaxf(ax, 0.f); ay = fmaxf(ay, 0.f);
#pragma unroll
        for (int oc2 = 0; oc2 < 5; oc2++) {
            float4 q = F3W[oc2 * 16 + m2];
            oo[oc2].x += q.x * ax + q.z * ay;
            oo[oc2].y += q.y * ax + q.w * ay;
        }
    }
    float* ob = out + (size_t)b * OUTC * NPIX + pix;
#pragma unroll
    for (int oc2 = 0; oc2 < 5; oc2++) {
        ob[(size_t)(2 * oc2) * NPIX]     = oo[oc2].x;
        ob[(size_t)(2 * oc2 + 1) * NPIX] = oo[oc2].y;
    }
}

extern "C" void kernel_launch(void* const* d_in, const int* in_sizes, int n_in,
                              void* d_out, int out_size, void* d_ws, size_t ws_size,
                              hipStream_t stream) {
    const float* x     = (const float*)d_in[0];
    const float* eattr = (const float*)d_in[3];
    const float* Wih0  = (const float*)d_in[4];
    const float* Whh0  = (const float*)d_in[5];
    const float* bih0  = (const float*)d_in[6];
    const float* bhh0  = (const float*)d_in[7];
    const float* Wih1  = (const float*)d_in[8];
    const float* Whh1  = (const float*)d_in[9];
    const float* bih1  = (const float*)d_in[10];
    const float* bhh1  = (const float*)d_in[11];
    const float* fc1w  = (const float*)d_in[12];
    const float* fc1b  = (const float*)d_in[13];
    const float* convw = (const float*)d_in[14];
    const float* convb = (const float*)d_in[15];
    const float* gparam= (const float*)d_in[16];
    const float* fc2w  = (const float*)d_in[17];
    const float* fc2b  = (const float*)d_in[18];
    const float* fc3w  = (const float*)d_in[19];
    const float* fc3b  = (const float*)d_in[20];

    float* P  = (float*)d_ws;
    float* FA = P + OFF_FEATS_A;
    float* FB = P + OFF_FEATS_B;

    prep_kernel<<<64, 256, 0, stream>>>(Wih0, Whh0, bih0, bhh0, Wih1, Whh1, bih1, bhh1,
                                        fc1w, fc1b, convw, convb, fc2w, fc2b, fc3w, fc3b,
                                        gparam, eattr, P);
    lstm_fc1_kernel<<<1024, 128, 0, stream>>>(x, P, FA);
    conv_fused_kernel<<<512, 256, 0, stream>>>(FA, FB, P, 0);
    conv_fused_kernel<<<512, 256, 0, stream>>>(FB, FA, P, 1);
    conv_fused_kernel<<<512, 256, 0, stream>>>(FA, FB, P, 2);
    conv_head_kernel<<<512, 256, 0, stream>>>(FB, P, (float*)d_out);
}